// Round 2
// baseline (1212.994 us; speedup 1.0000x reference)
//
#include <hip/hip_runtime.h>
#include <cstdint>
#include <cmath>

#define MDIM 4096
#define KDIM 4096
#define NDIM 16384
#define TEST_BOUND -2.053748910631823

typedef unsigned short u16;
typedef __attribute__((ext_vector_type(8))) short short8;
typedef __attribute__((ext_vector_type(16))) float floatx16;

// ---------- fp32 -> bf16 (RNE) conversion ----------
__device__ __forceinline__ u16 f2bf(float f) {
  union { float f; uint32_t u; } c; c.f = f;
  uint32_t r = c.u + 0x7fffu + ((c.u >> 16) & 1u);
  return (u16)(r >> 16);
}

__global__ __launch_bounds__(256) void cvt_kernel(const float4* __restrict__ in,
                                                  ushort4* __restrict__ out, int n4) {
  int stride = gridDim.x * 256;
  for (int i = blockIdx.x * 256 + threadIdx.x; i < n4; i += stride) {
    float4 v = in[i];
    ushort4 o;
    o.x = f2bf(v.x); o.y = f2bf(v.y); o.z = f2bf(v.z); o.w = f2bf(v.w);
    out[i] = o;
  }
}

// ---------- early-stat mask in STRICT f32 (match np f32 einsum semantics) ----------
__global__ __launch_bounds__(256) void stats_kernel(const float* __restrict__ x,
                                                    const float* __restrict__ w,
                                                    unsigned char* __restrict__ mask) {
  __shared__ float Xs[64][33];  // +1 pad kills bank conflicts on row reads
  __shared__ float Ws[64][33];
  const int bn = blockIdx.x;    // N/64 = 256
  const int bm = blockIdx.y;    // M/64 = 64
  const int t = threadIdx.x;
  for (int e = t; e < 64 * 32; e += 256) {
    int r = e >> 5, c = e & 31;
    Xs[r][c] = x[(size_t)(bm * 64 + r) * KDIM + c];
    Ws[r][c] = w[(size_t)(bn * 64 + r) * KDIM + c];
  }
  __syncthreads();
  const int tn = (t & 15) * 4;
  const int tm = (t >> 4) * 4;
  float y1[4][4] = {}, q[4][4] = {};
  for (int k = 0; k < 32; ++k) {
    float xv[4], wv[4], xx[4], ww[4];
#pragma unroll
    for (int i = 0; i < 4; ++i) { xv[i] = Xs[tm + i][k]; xx[i] = __fmul_rn(xv[i], xv[i]); }
#pragma unroll
    for (int j = 0; j < 4; ++j) { wv[j] = Ws[tn + j][k]; ww[j] = __fmul_rn(wv[j], wv[j]); }
#pragma unroll
    for (int i = 0; i < 4; ++i)
#pragma unroll
      for (int j = 0; j < 4; ++j) {
        y1[i][j] = __fadd_rn(y1[i][j], __fmul_rn(xv[i], wv[j]));
        q[i][j]  = __fadd_rn(q[i][j],  __fmul_rn(xx[i], ww[j]));
      }
  }
#pragma unroll
  for (int i = 0; i < 4; ++i)
#pragma unroll
    for (int j = 0; j < 4; ++j) {
      float mean = __fmul_rn(y1[i][j], 0.03125f);          // STATS_W=1, STATS_B=0
      float var  = __fsub_rn(__fmul_rn(q[i][j], 0.03125f), __fmul_rn(mean, mean));
      float varn = __fmul_rn(var, 0.03125f);
      float den  = __fsqrt_rn(fmaxf(varn, 1e-12f));
      float ts   = __fdiv_rn(mean, den);
      bool passed = ts < (float)TEST_BOUND;
      mask[(size_t)(bm * 64 + tm + i) * NDIM + (bn * 64 + tn + j)] = passed ? 1u : 0u;
    }
}

// ---------- bf16 MFMA GEMM: 256x256 tile, BK=64, 8 waves, 4-phase/K-tile ----------
// Round-2: same proven barrier/vmcnt/swizzle skeleton as round-1, but:
//  * 32x32x16 MFMA (2495 TF ceiling vs 2075 for 16x16x32; half the instructions)
//  * b-half1 reads issued in P1 with counted lgkmcnt(4) (service hides under C1)
//  * kn clamps dropped (overrun reads land in adjacent mapped ws regions, unused)
#define BM 256
#define BN 256
#define BK 64

typedef const __attribute__((address_space(1))) uint32_t* as1_u32p;
typedef __attribute__((address_space(3))) uint32_t* as3_u32p;

__device__ __forceinline__ void async_ld16(const void* g, void* l) {
  __builtin_amdgcn_global_load_lds((as1_u32p)g, (as3_u32p)l, 16, 0, 0);
}

// Stage one half-tile (128 rows x 64 cols bf16 = 16KB) = 2 loads/thread.
// LDS dest LINEAR; swizzle in SOURCE column: LDS element (row, c) holds logical
// (row, c ^ ((row&7)*8)). Readers apply the same XOR.
__device__ __forceinline__ void stage_half(const u16* __restrict__ src, size_t grow0,
                                           int k0, u16* lds, int tid) {
  const int r = tid >> 3;
  const int c = (((tid & 7) ^ (r & 7)) << 3);
  const u16* g0 = src + (grow0 + (size_t)r) * KDIM + (size_t)(k0 + c);
  u16* l0 = lds + (size_t)(tid & ~63) * 8;
  async_ld16(g0, l0);
  async_ld16(g0 + (size_t)64 * KDIM, l0 + 4096);
}

__global__ __launch_bounds__(512, 2) void gemm_kernel(const u16* __restrict__ A,
                                                      const u16* __restrict__ B,
                                                      const float* __restrict__ bias,
                                                      const unsigned char* __restrict__ mask,
                                                      float* __restrict__ C) {
  __shared__ __align__(16) u16 As[2][BM * BK];
  __shared__ __align__(16) u16 Bs[2][BN * BK];

  // T1 bijective XCD swizzle (nwg = 1024, %8==0); bm fastest -> B panel L2-resident
  const int bid = blockIdx.x;
  const int swz = (bid & 7) * 128 + (bid >> 3);
  const int bm = swz & 15;          // M/256 = 16
  const int bn = swz >> 4;          // N/256 = 64

  const int tid = threadIdx.x;
  const int w = tid >> 6, l = tid & 63;
  const int ln = l & 31;            // row/col within 32-frag
  const int kh = (l >> 5) << 3;     // k-half offset (elements)
  const int wm_i = w >> 2;          // 2 wave-rows
  const int wn_i = w & 3;           // 4 wave-cols
  const int swx = (ln & 7) << 3;    // read-side swizzle XOR (elements)

  // fragment read columns per 16-k slice
  int ck[4];
#pragma unroll
  for (int ks = 0; ks < 4; ++ks) ck[ks] = (ks * 16 + kh) ^ swx;
  // A stripes: tile row = wm_i*32 + s*64 + ln (s=0..3); s&1 selects +64 within half,
  // s>>1 selects half (+8192 elements). B: j=0 half0, j=1 half1, row wn_i*32+ln.
  const int arow = (wm_i * 32 + ln) * 64;
  const int brow = (wn_i * 32 + ln) * 64;

  const size_t abase = (size_t)bm * BM;
  const size_t bbase = (size_t)bn * BN;

  floatx16 acc[4][2];
#pragma unroll
  for (int i = 0; i < 4; ++i)
#pragma unroll
    for (int j = 0; j < 2; ++j)
#pragma unroll
      for (int r = 0; r < 16; ++r) acc[i][j][r] = 0.f;

  // ---- prologue: tile0 halves A0,B0,B1,A1; tile1 halves A0,B0,B1 ----
  stage_half(A, abase,       0,  &As[0][0],    tid);
  stage_half(B, bbase,       0,  &Bs[0][0],    tid);
  stage_half(B, bbase + 128, 0,  &Bs[0][8192], tid);
  stage_half(A, abase + 128, 0,  &As[0][8192], tid);
  asm volatile("s_waitcnt vmcnt(4)" ::: "memory");
  stage_half(A, abase,       BK, &As[1][0],    tid);
  stage_half(B, bbase,       BK, &Bs[1][0],    tid);
  stage_half(B, bbase + 128, BK, &Bs[1][8192], tid);
  asm volatile("s_waitcnt vmcnt(6)" ::: "memory");   // tile0 landed; 3 halves in flight
  __builtin_amdgcn_s_barrier();

  short8 a[2][4], b[2][4];

  for (int kt = 0; kt < KDIM / BK; ++kt) {   // 64 K-tiles
    u16* Ab = &As[kt & 1][0];
    u16* Bb = &Bs[kt & 1][0];
    const int kn1 = (kt + 1) * BK;   // no clamp: tail overrun lands in mapped ws, unused
    const int kn2 = (kt + 2) * BK;

    // ---- P1: read A stripes 0,1 + B j=0 AND j=1 (b1 counted-outstanding);
    //          stage (kt+1, A1) into the OTHER buffer ----
#pragma unroll
    for (int s = 0; s < 2; ++s)
#pragma unroll
      for (int ks = 0; ks < 4; ++ks)
        a[s][ks] = *(const short8*)&Ab[arow + s * 4096 + ck[ks]];
#pragma unroll
    for (int ks = 0; ks < 4; ++ks) b[0][ks] = *(const short8*)&Bb[brow + ck[ks]];
#pragma unroll
    for (int ks = 0; ks < 4; ++ks) b[1][ks] = *(const short8*)&Bb[brow + 8192 + ck[ks]];
    stage_half(A, abase + 128, kn1, &As[(kt + 1) & 1][8192], tid);
    __builtin_amdgcn_s_barrier();
    asm volatile("s_waitcnt lgkmcnt(4)" ::: "memory");  // a,b0 done; b1 may be in flight
    __builtin_amdgcn_sched_barrier(0);
    __builtin_amdgcn_s_setprio(1);
#pragma unroll
    for (int ks = 0; ks < 4; ++ks)
#pragma unroll
      for (int s = 0; s < 2; ++s)
        acc[s][0] = __builtin_amdgcn_mfma_f32_32x32x16_bf16(a[s][ks], b[0][ks], acc[s][0], 0, 0, 0);
    __builtin_amdgcn_s_setprio(0);
    __builtin_amdgcn_sched_barrier(0);
    __builtin_amdgcn_s_barrier();

    // ---- P2: no reads; stage (kt+2, A0) over consumed A-half0 ----
    stage_half(A, abase, kn2, &As[kt & 1][0], tid);
    __builtin_amdgcn_s_barrier();
    asm volatile("s_waitcnt lgkmcnt(0)" ::: "memory");  // b1 complete
    __builtin_amdgcn_sched_barrier(0);
    __builtin_amdgcn_s_setprio(1);
#pragma unroll
    for (int ks = 0; ks < 4; ++ks)
#pragma unroll
      for (int s = 0; s < 2; ++s)
        acc[s][1] = __builtin_amdgcn_mfma_f32_32x32x16_bf16(a[s][ks], b[1][ks], acc[s][1], 0, 0, 0);
    __builtin_amdgcn_s_setprio(0);
    __builtin_amdgcn_sched_barrier(0);
    __builtin_amdgcn_s_barrier();

    // ---- P3: reload a[] with A stripes 2,3 (half1); stage (kt+2, B0) ----
#pragma unroll
    for (int s = 0; s < 2; ++s)
#pragma unroll
      for (int ks = 0; ks < 4; ++ks)
        a[s][ks] = *(const short8*)&Ab[8192 + arow + s * 4096 + ck[ks]];
    stage_half(B, bbase, kn2, &Bs[kt & 1][0], tid);
    __builtin_amdgcn_s_barrier();
    asm volatile("s_waitcnt lgkmcnt(0)" ::: "memory");
    __builtin_amdgcn_sched_barrier(0);
    __builtin_amdgcn_s_setprio(1);
#pragma unroll
    for (int ks = 0; ks < 4; ++ks)
#pragma unroll
      for (int s = 0; s < 2; ++s)
        acc[2 + s][0] = __builtin_amdgcn_mfma_f32_32x32x16_bf16(a[s][ks], b[0][ks], acc[2 + s][0], 0, 0, 0);
    __builtin_amdgcn_s_setprio(0);
    __builtin_amdgcn_sched_barrier(0);
    __builtin_amdgcn_s_barrier();

    // ---- P4: stage (kt+2, B1); MFMA from regs; counted vmcnt, NEVER 0 ----
    stage_half(B, bbase + 128, kn2, &Bs[kt & 1][8192], tid);
    __builtin_amdgcn_s_barrier();
    __builtin_amdgcn_s_setprio(1);
#pragma unroll
    for (int ks = 0; ks < 4; ++ks)
#pragma unroll
      for (int s = 0; s < 2; ++s)
        acc[2 + s][1] = __builtin_amdgcn_mfma_f32_32x32x16_bf16(a[s][ks], b[1][ks], acc[2 + s][1], 0, 0, 0);
    __builtin_amdgcn_s_setprio(0);
    // drain tile kt+1's 4 halves; leave tile kt+2's 3 halves (6 loads) in flight
    asm volatile("s_waitcnt vmcnt(6)" ::: "memory");
    __builtin_amdgcn_sched_barrier(0);
    __builtin_amdgcn_s_barrier();
  }

  // ---- epilogue: 32x32 C/D layout: col=lane&31, row=(reg&3)+8*(reg>>2)+4*(lane>>5) ----
  float bv[2];
#pragma unroll
  for (int j = 0; j < 2; ++j) bv[j] = bias[bbase + wn_i * 32 + j * 128 + ln];
  const int rbase = (l >> 5) * 4;
#pragma unroll
  for (int i = 0; i < 4; ++i) {
    const size_t growf = abase + (size_t)(wm_i * 32 + i * 64);
#pragma unroll
    for (int j = 0; j < 2; ++j) {
      const size_t coloff = bbase + (size_t)(wn_i * 32 + j * 128 + ln);
#pragma unroll
      for (int r = 0; r < 16; ++r) {
        const int mloc = (r & 3) + 8 * (r >> 2) + rbase;
        const size_t off = (growf + mloc) * NDIM + coloff;
        float y = acc[i][j][r] + bv[j];
        C[off] = mask[off] ? 0.0f : y;
      }
    }
  }
}

extern "C" void kernel_launch(void* const* d_in, const int* in_sizes, int n_in,
                              void* d_out, int out_size, void* d_ws, size_t ws_size,
                              hipStream_t stream) {
  const float* x = (const float*)d_in[0];
  const float* w = (const float*)d_in[1];
  const float* bias = (const float*)d_in[2];
  float* out = (float*)d_out;

  // ws layout: xbf (32MB) | wbf (128MB) | mask (64MB) = 224MB
  u16* xbf = (u16*)d_ws;
  u16* wbf = xbf + (size_t)MDIM * KDIM;
  unsigned char* mask = (unsigned char*)(wbf + (size_t)NDIM * KDIM);

  cvt_kernel<<<2048, 256, 0, stream>>>((const float4*)x, (ushort4*)xbf, MDIM * KDIM / 4);
  cvt_kernel<<<8192, 256, 0, stream>>>((const float4*)w, (ushort4*)wbf, NDIM * KDIM / 4);
  stats_kernel<<<dim3(NDIM / 64, MDIM / 64), 256, 0, stream>>>(x, w, mask);
  gemm_kernel<<<(MDIM / BM) * (NDIM / BN), 512, 0, stream>>>(xbf, wbf, bias, mask, out);
}

// Round 3
// 1109.622 us; speedup vs baseline: 1.0932x; 1.0932x over previous
//
#include <hip/hip_runtime.h>
#include <cstdint>
#include <cmath>

#define MDIM 4096
#define KDIM 4096
#define NDIM 16384
#define TEST_BOUND -2.053748910631823

typedef unsigned short u16;
typedef __attribute__((ext_vector_type(8))) short short8;
typedef __attribute__((ext_vector_type(4))) float floatx4;

// ---------- fp32 -> bf16 (RNE) conversion ----------
__device__ __forceinline__ u16 f2bf(float f) {
  union { float f; uint32_t u; } c; c.f = f;
  uint32_t r = c.u + 0x7fffu + ((c.u >> 16) & 1u);
  return (u16)(r >> 16);
}

// ---------- fused prep: bf16 convert (x and w) + early-stat mask ----------
// cvt and stats are mutually independent (stats reads the ORIGINAL f32 x,w),
// so one kernel interleaves the BW-bound cvt stream with the VALU-bound stats
// stream: resident waves in their cvt phase overlap waves in their stats phase.
// Stats math is BYTE-IDENTICAL to the verified strict-f32 version: numpy f32
// einsum semantics, never-contracted _rn intrinsics — mask bits must not move.
__global__ __launch_bounds__(256) void prep_kernel(const float* __restrict__ x,
                                                   const float* __restrict__ w,
                                                   u16* __restrict__ xbf,
                                                   u16* __restrict__ wbf,
                                                   unsigned char* __restrict__ mask) {
  const int bn = blockIdx.x;    // N/64 = 256
  const int bm = blockIdx.y;    // M/64 = 64
  const int t = threadIdx.x;

  // ---- part 1: grid-stride bf16 conversion share (x then w regions) ----
  {
    const size_t NX4 = (size_t)MDIM * KDIM / 4;          // 4.19M float4
    const size_t NTOT = NX4 + (size_t)NDIM * KDIM / 4;   // 20.97M float4
    const size_t lbid = (size_t)blockIdx.y * gridDim.x + blockIdx.x;
    const size_t stride = (size_t)gridDim.x * gridDim.y * 256;
    for (size_t i = lbid * 256 + t; i < NTOT; i += stride) {
      float4 v;
      if (i < NX4) v = ((const float4*)x)[i];
      else         v = ((const float4*)w)[i - NX4];
      ushort4 o;
      o.x = f2bf(v.x); o.y = f2bf(v.y); o.z = f2bf(v.z); o.w = f2bf(v.w);
      if (i < NX4) ((ushort4*)xbf)[i] = o;
      else         ((ushort4*)wbf)[i - NX4] = o;
    }
  }

  // ---- part 2: strict-f32 early-stat mask tile (unchanged math) ----
  __shared__ float Xs[64][33];  // +1 pad kills bank conflicts on row reads
  __shared__ float Ws[64][33];
  for (int e = t; e < 64 * 32; e += 256) {
    int r = e >> 5, c = e & 31;
    Xs[r][c] = x[(size_t)(bm * 64 + r) * KDIM + c];
    Ws[r][c] = w[(size_t)(bn * 64 + r) * KDIM + c];
  }
  __syncthreads();
  const int tn = (t & 15) * 4;
  const int tm = (t >> 4) * 4;
  float y1[4][4] = {}, q[4][4] = {};
  for (int k = 0; k < 32; ++k) {
    float xv[4], wv[4], xx[4], ww[4];
#pragma unroll
    for (int i = 0; i < 4; ++i) { xv[i] = Xs[tm + i][k]; xx[i] = __fmul_rn(xv[i], xv[i]); }
#pragma unroll
    for (int j = 0; j < 4; ++j) { wv[j] = Ws[tn + j][k]; ww[j] = __fmul_rn(wv[j], wv[j]); }
#pragma unroll
    for (int i = 0; i < 4; ++i)
#pragma unroll
      for (int j = 0; j < 4; ++j) {
        y1[i][j] = __fadd_rn(y1[i][j], __fmul_rn(xv[i], wv[j]));
        q[i][j]  = __fadd_rn(q[i][j],  __fmul_rn(xx[i], ww[j]));
      }
  }
#pragma unroll
  for (int i = 0; i < 4; ++i)
#pragma unroll
    for (int j = 0; j < 4; ++j) {
      float mean = __fmul_rn(y1[i][j], 0.03125f);          // STATS_W=1, STATS_B=0
      float var  = __fsub_rn(__fmul_rn(q[i][j], 0.03125f), __fmul_rn(mean, mean));
      float varn = __fmul_rn(var, 0.03125f);
      float den  = __fsqrt_rn(fmaxf(varn, 1e-12f));
      float ts   = __fdiv_rn(mean, den);
      bool passed = ts < (float)TEST_BOUND;
      mask[(size_t)(bm * 64 + tm + i) * NDIM + (bn * 64 + tn + j)] = passed ? 1u : 0u;
    }
}

// ---------- bf16 MFMA GEMM: 256x256 tile, BK=64, 8 waves, 4-phase/K-tile ----------
// ROUND-1 VERBATIM (measured 618 us, SQ_LDS_BANK_CONFLICT = 0). Round-2's
// 32x32x16 variant regressed (+65 us, 5e7 conflicts) — reverted.
#define BM 256
#define BN 256
#define BK 64

typedef const __attribute__((address_space(1))) uint32_t* as1_u32p;
typedef __attribute__((address_space(3))) uint32_t* as3_u32p;

__device__ __forceinline__ void async_ld16(const void* g, void* l) {
  // LDS dest: wave-uniform base + lane*16B (HW); global source is per-lane.
  __builtin_amdgcn_global_load_lds((as1_u32p)g, (as3_u32p)l, 16, 0, 0);
}

// Stage one half-tile (128 rows x 64 cols bf16 = 16KB) = 2 loads/thread.
// LDS dest LINEAR; swizzle in SOURCE column: LDS element (row, c) holds logical
// (row, c ^ ((row&7)*8)). Readers apply the same XOR.
__device__ __forceinline__ void stage_half(const u16* __restrict__ src, size_t grow0,
                                           int k0, u16* lds, int tid) {
  const int r = tid >> 3;                         // region row 0..63 (load1: +64)
  const int c = (((tid & 7) ^ (r & 7)) << 3);     // inverse-swizzled source col (elems)
  const u16* g0 = src + (grow0 + (size_t)r) * KDIM + (size_t)(k0 + c);
  u16* l0 = lds + (size_t)(tid & ~63) * 8;        // wave-uniform LDS base
  async_ld16(g0, l0);
  async_ld16(g0 + (size_t)64 * KDIM, l0 + 4096);  // rows 64..127, +8192B
}

__global__ __launch_bounds__(512, 2) void gemm_kernel(const u16* __restrict__ A,
                                                      const u16* __restrict__ B,
                                                      const float* __restrict__ bias,
                                                      const unsigned char* __restrict__ mask,
                                                      float* __restrict__ C) {
  // 2 buffers x (A 256x64 + B 256x64) bf16 = 128 KiB
  __shared__ __align__(16) u16 As[2][BM * BK];
  __shared__ __align__(16) u16 Bs[2][BN * BK];

  // T1: bijective XCD swizzle (nwg = 1024, 1024%8 == 0). bm fastest: 16 consecutive
  // blocks (one XCD round) share one 2MB B panel -> L2-resident.
  const int bid = blockIdx.x;
  const int swz = (bid & 7) * ((MDIM / BM) * (NDIM / BN) / 8) + (bid >> 3);
  const int bm = swz & 15;          // M/256 = 16
  const int bn = swz >> 4;          // N/256 = 64

  const int tid = threadIdx.x;
  const int w = tid >> 6, l = tid & 63;
  const int lm = l & 15, quad = l >> 4;
  const int wm_i = w >> 2;          // 2 wave-rows (each 8 interleaved 16-row stripes)
  const int wn_i = w & 3;           // 4 wave-cols
  const int sw8 = (lm & 7) << 3;    // read-side swizzle, in elements
  const int c0 = (quad * 8) ^ sw8;        // k-slice 0 frag col
  const int c1 = (32 + quad * 8) ^ sw8;   // k-slice 1 frag col

  const size_t abase = (size_t)bm * BM;
  const size_t bbase = (size_t)bn * BN;

  floatx4 acc[8][4];
#pragma unroll
  for (int i = 0; i < 8; ++i)
#pragma unroll
    for (int j = 0; j < 4; ++j) acc[i][j] = (floatx4){0.f, 0.f, 0.f, 0.f};

  // ---- prologue: tile0 halves A0,B0,B1,A1; tile1 halves A0,B0,B1 ----
  stage_half(A, abase,       0,  &As[0][0],    tid);
  stage_half(B, bbase,       0,  &Bs[0][0],    tid);
  stage_half(B, bbase + 128, 0,  &Bs[0][8192], tid);
  stage_half(A, abase + 128, 0,  &As[0][8192], tid);
  asm volatile("s_waitcnt vmcnt(4)" ::: "memory");
  stage_half(A, abase,       BK, &As[1][0],    tid);
  stage_half(B, bbase,       BK, &Bs[1][0],    tid);
  stage_half(B, bbase + 128, BK, &Bs[1][8192], tid);
  asm volatile("s_waitcnt vmcnt(6)" ::: "memory");   // tile0 fully landed; 3 halves in flight
  __builtin_amdgcn_s_barrier();

  short8 a[4][2], b[4][2];

  for (int kt = 0; kt < KDIM / BK; ++kt) {   // 64 K-tiles
    u16* Ab = &As[kt & 1][0];
    u16* Bb = &Bs[kt & 1][0];
    // clamp staged tile index so vmcnt counts stay uniform & addresses in-bounds
    const int kn1 = (kt + 1 <= 63 ? kt + 1 : 63) * BK;
    const int kn2 = (kt + 2 <= 63 ? kt + 2 : 63) * BK;

    // ---- P1: read A-half0 frags 0-3 + B-half0 frags 0-1; stage (kt+1, A1) ----
#pragma unroll
    for (int i4 = 0; i4 < 4; ++i4) {
      const int row = wm_i * 16 + i4 * 32 + lm;
      a[i4][0] = *(const short8*)&Ab[row * 64 + c0];
      a[i4][1] = *(const short8*)&Ab[row * 64 + c1];
    }
#pragma unroll
    for (int j = 0; j < 2; ++j) {
      const int row = wn_i * 16 + j * 64 + lm;
      b[j][0] = *(const short8*)&Bb[row * 64 + c0];
      b[j][1] = *(const short8*)&Bb[row * 64 + c1];
    }
    stage_half(A, abase + 128, kn1, &As[(kt + 1) & 1][8192], tid);
    __builtin_amdgcn_s_barrier();
    asm volatile("s_waitcnt lgkmcnt(0)" ::: "memory");
    __builtin_amdgcn_sched_barrier(0);
    __builtin_amdgcn_s_setprio(1);
#pragma unroll
    for (int i4 = 0; i4 < 4; ++i4)
#pragma unroll
      for (int j = 0; j < 2; ++j) {
        acc[i4][j] = __builtin_amdgcn_mfma_f32_16x16x32_bf16(a[i4][0], b[j][0], acc[i4][j], 0, 0, 0);
        acc[i4][j] = __builtin_amdgcn_mfma_f32_16x16x32_bf16(a[i4][1], b[j][1], acc[i4][j], 0, 0, 0);
      }
    __builtin_amdgcn_s_setprio(0);
    __builtin_amdgcn_s_barrier();

    // ---- P2: read B-half1 frags 2-3; stage (kt+2, A0) ----
#pragma unroll
    for (int j = 2; j < 4; ++j) {
      const int row = wn_i * 16 + j * 64 + lm;
      b[j][0] = *(const short8*)&Bb[row * 64 + c0];
      b[j][1] = *(const short8*)&Bb[row * 64 + c1];
    }
    stage_half(A, abase, kn2, &As[kt & 1][0], tid);
    __builtin_amdgcn_s_barrier();
    asm volatile("s_waitcnt lgkmcnt(0)" ::: "memory");
    __builtin_amdgcn_sched_barrier(0);
    __builtin_amdgcn_s_setprio(1);
#pragma unroll
    for (int i4 = 0; i4 < 4; ++i4)
#pragma unroll
      for (int j = 2; j < 4; ++j) {
        acc[i4][j] = __builtin_amdgcn_mfma_f32_16x16x32_bf16(a[i4][0], b[j][0], acc[i4][j], 0, 0, 0);
        acc[i4][j] = __builtin_amdgcn_mfma_f32_16x16x32_bf16(a[i4][1], b[j][1], acc[i4][j], 0, 0, 0);
      }
    __builtin_amdgcn_s_setprio(0);
    __builtin_amdgcn_s_barrier();

    // ---- P3: read A-half1 frags 4-7; stage (kt+2, B0) ----
#pragma unroll
    for (int i4 = 0; i4 < 4; ++i4) {
      const int row = wm_i * 16 + (4 + i4) * 32 + lm;
      a[i4][0] = *(const short8*)&Ab[row * 64 + c0];
      a[i4][1] = *(const short8*)&Ab[row * 64 + c1];
    }
    stage_half(B, bbase, kn2, &Bs[kt & 1][0], tid);
    __builtin_amdgcn_s_barrier();
    asm volatile("s_waitcnt lgkmcnt(0)" ::: "memory");
    __builtin_amdgcn_sched_barrier(0);
    __builtin_amdgcn_s_setprio(1);
#pragma unroll
    for (int i4 = 0; i4 < 4; ++i4)
#pragma unroll
      for (int j = 0; j < 2; ++j) {
        acc[4 + i4][j] = __builtin_amdgcn_mfma_f32_16x16x32_bf16(a[i4][0], b[j][0], acc[4 + i4][j], 0, 0, 0);
        acc[4 + i4][j] = __builtin_amdgcn_mfma_f32_16x16x32_bf16(a[i4][1], b[j][1], acc[4 + i4][j], 0, 0, 0);
      }
    __builtin_amdgcn_s_setprio(0);
    __builtin_amdgcn_s_barrier();

    // ---- P4: stage (kt+2, B1); MFMA from regs; counted vmcnt, NEVER 0 ----
    stage_half(B, bbase + 128, kn2, &Bs[kt & 1][8192], tid);
    __builtin_amdgcn_s_barrier();
    __builtin_amdgcn_s_setprio(1);
#pragma unroll
    for (int i4 = 0; i4 < 4; ++i4)
#pragma unroll
      for (int j = 2; j < 4; ++j) {
        acc[4 + i4][j] = __builtin_amdgcn_mfma_f32_16x16x32_bf16(a[i4][0], b[j][0], acc[4 + i4][j], 0, 0, 0);
        acc[4 + i4][j] = __builtin_amdgcn_mfma_f32_16x16x32_bf16(a[i4][1], b[j][1], acc[4 + i4][j], 0, 0, 0);
      }
    __builtin_amdgcn_s_setprio(0);
    // drain tile kt+1's 4 halves; leave tile kt+2's 3 halves (6 loads) in flight
    asm volatile("s_waitcnt vmcnt(6)" ::: "memory");
    __builtin_amdgcn_s_barrier();
  }

  // ---- epilogue: C/D layout col=lane&15, row=quad*4+reg ----
  float bv[4];
#pragma unroll
  for (int j = 0; j < 4; ++j) bv[j] = bias[bbase + wn_i * 16 + j * 64 + lm];
#pragma unroll
  for (int i = 0; i < 8; ++i) {
    const int mrow = wm_i * 16 + i * 32 + quad * 4;
#pragma unroll
    for (int r = 0; r < 4; ++r) {
      const size_t gm = abase + (size_t)(mrow + r);
      const size_t rowoff = gm * NDIM + bbase;
#pragma unroll
      for (int j = 0; j < 4; ++j) {
        const size_t off = rowoff + (size_t)(wn_i * 16 + j * 64 + lm);
        float y = acc[i][j][r] + bv[j];
        C[off] = mask[off] ? 0.0f : y;
      }
    }
  }
}

extern "C" void kernel_launch(void* const* d_in, const int* in_sizes, int n_in,
                              void* d_out, int out_size, void* d_ws, size_t ws_size,
                              hipStream_t stream) {
  const float* x = (const float*)d_in[0];
  const float* w = (const float*)d_in[1];
  const float* bias = (const float*)d_in[2];
  float* out = (float*)d_out;

  // ws layout: xbf (32MB) | wbf (128MB) | mask (64MB) = 224MB
  u16* xbf = (u16*)d_ws;
  u16* wbf = xbf + (size_t)MDIM * KDIM;
  unsigned char* mask = (unsigned char*)(wbf + (size_t)NDIM * KDIM);

  prep_kernel<<<dim3(NDIM / 64, MDIM / 64), 256, 0, stream>>>(x, w, xbf, wbf, mask);
  gemm_kernel<<<(MDIM / BM) * (NDIM / BN), 512, 0, stream>>>(xbf, wbf, bias, mask, out);
}